// Round 8
// baseline (1216.288 us; speedup 1.0000x reference)
//
#include <hip/hip_runtime.h>
#include <math.h>

// Problem constants
#define BN 16
#define HWSZ 16384
#define NC 80
#define KK 100

typedef _Float16 f16;
typedef _Float16 f16x2 __attribute__((ext_vector_type(2)));
typedef _Float16 f16x4 __attribute__((ext_vector_type(4)));
typedef _Float16 f16x8 __attribute__((ext_vector_type(8)));
typedef float    f32x4 __attribute__((ext_vector_type(4)));
typedef unsigned int uint;

// ---- workspace layout (float units) ----
#define WS_CLS   0
#define CLS_SZ   (BN*NC*HWSZ)
#define WS_REG   (WS_CLS + CLS_SZ)
#define REG_SZ   (BN*2*HWSZ)
#define WS_WH    (WS_REG + REG_SZ)
#define WH_SZ    (BN*2*HWSZ)
#define WS_SC    (WS_WH + WH_SZ)
#define SC_SZ    (BN*HWSZ)
#define WS_CAT   (WS_SC + SC_SZ)
#define CAT_SZ   (BN*HWSZ)
#define WS_W1H   (WS_CAT + CAT_SZ)             // f16 3*9*64*64 -> 55296 floats/plane
#define W1F      (110592/2)
#define WS_W1L   (WS_W1H + W1F)
#define WS_W2H   (WS_W1L + W1F)                // f16 112*64 (padded) -> 3584 floats/plane
#define W2F      (7168/2)
#define WS_W2L   (WS_W2H + W2F)

// scaling: x*16, w*256 -> acc = 4096*true
#define SCL_X   16.0f
#define SCL_W   256.0f
#define INV_ACC (1.0f/4096.0f)

// ---------------------------------------------------------------------------
// Prep: split weights to fp16 hi/lo (scaled by 256).
// w1: [br][s=3dy+dx][co][ci].  w2 padded 112 rows: [0..79]=cls, [80..81]=reg,
// [96..97]=wh, rest 0.
// ---------------------------------------------------------------------------
__global__ void k_prep(const float* __restrict__ cw1, const float* __restrict__ rw1,
                       const float* __restrict__ ww1, const float* __restrict__ cw2,
                       const float* __restrict__ rw2, const float* __restrict__ ww2,
                       f16* __restrict__ w1h, f16* __restrict__ w1l,
                       f16* __restrict__ w2h, f16* __restrict__ w2l) {
    int idx = blockIdx.x * 256 + threadIdx.x;
    if (idx < 3*9*64*64) {
        int ci = idx & 63, co = (idx >> 6) & 63;
        int s  = (idx >> 12) % 9, br = idx / 36864;
        const float* src = (br == 0) ? cw1 : (br == 1 ? rw1 : ww1);
        float v = src[(co*64 + ci)*9 + s] * SCL_W;
        f16 h = (f16)v;
        w1h[idx] = h; w1l[idx] = (f16)(v - (float)h);
    }
    int j = idx - 3*9*64*64;
    if (j >= 0 && j < 112*64) {
        int ci = j & 63, row = j >> 6;
        float v = 0.f;
        if (row < 80)                    v = cw2[row*64 + ci];
        else if (row < 82)               v = rw2[(row-80)*64 + ci];
        else if (row >= 96 && row < 98)  v = ww2[(row-96)*64 + ci];
        v *= SCL_W;
        f16 h = (f16)v;
        w2h[j] = h; w2l[j] = (f16)(v - (float)h);
    }
}

// ---------------------------------------------------------------------------
// Fused MFMA conv. grid (y=128, b=16), block 256 (4 waves; wave w: px[32w,+32)).
// r7 post-mortem: 72% stall — B-fragment L2 loads in the MFMA dependence
// shadow with only ~1.85 blocks/CU resident (37.9 KB LDS cap). Fix = occupancy:
// LDS 18.7 KB (single-buffered A row + conv2 in two 64-px half-passes, R
// aliased over A) -> 4+ blocks/CU so waves cover each other's latency.
// Same MFMA term order as r7 -> bit-identical outputs.
// ---------------------------------------------------------------------------
#define A_STRIDE 36                  // f16, per px row (32 ci + pad)
#define AL_OFF   4680                // f16 offset of lo plane (130*36)
__global__ __launch_bounds__(256) void k_conv(
    const float* __restrict__ x,
    const f16* __restrict__ w1h, const f16* __restrict__ w1l,
    const f16* __restrict__ w2h, const f16* __restrict__ w2l,
    const float* __restrict__ b1c, const float* __restrict__ b1r, const float* __restrict__ b1w,
    const float* __restrict__ b2c, const float* __restrict__ b2r, const float* __restrict__ b2w,
    float* __restrict__ cls_o, float* __restrict__ reg_o, float* __restrict__ wh_o)
{
    __shared__ char smem[18752] __attribute__((aligned(16)));
    f16* AH = (f16*)smem;                 // [130][36] hi
    f16* AL = (f16*)smem + AL_OFF;        // [130][36] lo
    // epilogue aliases: R half-tile [64][72] hi + lo
    f16* Rh = (f16*)smem;
    f16* Rl = (f16*)smem + 4608;

    const int y = blockIdx.x, b = blockIdx.y;
    const int tid = threadIdx.x;
    const int w = tid >> 6, lane = tid & 63;
    const int l15 = lane & 15, quad = lane >> 4;
    const int wbase = w * 32;

    static const int CS[6] = {0,0,0,1,1,1};
    static const int RS[6] = {0,1,2,0,1,2};

    for (int br = 0; br < 3; br++) {
        f32x4 acc[2][4];
        #pragma unroll
        for (int m = 0; m < 2; m++)
            #pragma unroll
            for (int n = 0; n < 4; n++) acc[m][n] = (f32x4){0.f,0.f,0.f,0.f};

        for (int si = 0; si < 6; si++) {
            __syncthreads();                 // prior compute / R reads done
            if (si == 0 && tid < 72) {       // zero px guard rows (slots 0,129)
                int plane = tid / 36, rem = tid % 36;
                int row = (rem < 18) ? 0 : 129, wd = rem % 18;
                ((uint*)smem)[plane*(AL_OFF/2) + row*18 + wd] = 0u;
            }
            {   // stage input row gy, chunk: 32 ci x 128 px, hi/lo split
                const int gy = y - 1 + RS[si];
                const bool ok = (gy >= 0) && (gy < 128);
                const float* xp = x + ((size_t)(b*64 + CS[si]*32)*128 + gy)*128;
                f16x2* dh = (f16x2*)AH;
                f16x2* dl = (f16x2*)AL;
                #pragma unroll
                for (int e0 = 0; e0 < 2048; e0 += 256) {
                    int e = e0 + tid;
                    int px = e & 127, cp = e >> 7;
                    float v0 = 0.f, v1 = 0.f;
                    if (ok) { v0 = xp[(size_t)(2*cp)*HWSZ + px]*SCL_X;
                              v1 = xp[(size_t)(2*cp+1)*HWSZ + px]*SCL_X; }
                    f16 h0 = (f16)v0, h1 = (f16)v1;
                    f16 l0 = (f16)(v0 - (float)h0), l1 = (f16)(v1 - (float)h1);
                    int wi = (px + 1)*(A_STRIDE/2) + cp;
                    dh[wi] = (f16x2){h0, h1};
                    dl[wi] = (f16x2){l0, l1};
                }
            }
            __syncthreads();
            // ---- compute on staged row ----
            const int chunk = CS[si], r = RS[si];
            #pragma unroll
            for (int dx = 0; dx < 3; dx++) {
                const int s = r*3 + dx;
                f16x8 ah[2], al[2];
                #pragma unroll
                for (int m = 0; m < 2; m++) {
                    int off = (wbase + m*16 + l15 + dx)*A_STRIDE + quad*8;
                    f16x4 h0 = *(const f16x4*)(AH + off);
                    f16x4 h1 = *(const f16x4*)(AH + off + 4);
                    f16x4 u0 = *(const f16x4*)(AL + off);
                    f16x4 u1 = *(const f16x4*)(AL + off + 4);
                    ah[m] = __builtin_shufflevector(h0, h1, 0,1,2,3,4,5,6,7);
                    al[m] = __builtin_shufflevector(u0, u1, 0,1,2,3,4,5,6,7);
                }
                const f16* gbh = w1h + ((size_t)((br*9 + s)*64 + l15))*64 + chunk*32 + quad*8;
                const f16* gbl = w1l + ((size_t)((br*9 + s)*64 + l15))*64 + chunk*32 + quad*8;
                #pragma unroll
                for (int n = 0; n < 4; n++) {
                    f16x8 bh = *(const f16x8*)(gbh + n*1024);
                    f16x8 bl = *(const f16x8*)(gbl + n*1024);
                    #pragma unroll
                    for (int m = 0; m < 2; m++) {
                        acc[m][n] = __builtin_amdgcn_mfma_f32_16x16x32_f16(ah[m], bh, acc[m][n], 0,0,0);
                        acc[m][n] = __builtin_amdgcn_mfma_f32_16x16x32_f16(ah[m], bl, acc[m][n], 0,0,0);
                        acc[m][n] = __builtin_amdgcn_mfma_f32_16x16x32_f16(al[m], bh, acc[m][n], 0,0,0);
                    }
                }
            }
        }

        // ---- epilogue: two 64-px half passes (R aliased over A region) ----
        const float* b1 = (br == 0) ? b1c : (br == 1 ? b1r : b1w);
        float b1v[4];
        #pragma unroll
        for (int n = 0; n < 4; n++) b1v[n] = b1[n*16 + l15];
        const int NT     = (br == 0) ? 5 : 1;
        const int rowoff = (br == 0) ? 0 : (br == 1 ? 80 : 96);

        for (int h = 0; h < 2; h++) {
            __syncthreads();                 // prior compute/conv2 reads done
            if ((w >> 1) == h) {             // writer waves for this half
                #pragma unroll
                for (int m = 0; m < 2; m++)
                    #pragma unroll
                    for (int n = 0; n < 4; n++)
                        #pragma unroll
                        for (int rg = 0; rg < 4; rg++) {
                            float t = fmaxf(acc[m][n][rg]*INV_ACC + b1v[n], 0.f) * SCL_X;
                            f16 hh = (f16)t;
                            int pxl = (w & 1)*32 + m*16 + quad*4 + rg;
                            int co  = n*16 + l15;
                            Rh[pxl*72 + co] = hh;
                            Rl[pxl*72 + co] = (f16)(t - (float)hh);
                        }
            }
            __syncthreads();
            // conv2 on this half: wave w owns m-tile w (px_local w*16..+16)
            f32x4 a2[5];
            #pragma unroll
            for (int n = 0; n < 5; n++) a2[n] = (f32x4){0.f,0.f,0.f,0.f};
            #pragma unroll
            for (int kc = 0; kc < 64; kc += 32) {
                int off = (w*16 + l15)*72 + kc + quad*8;
                f16x8 xh = *(const f16x8*)(Rh + off);
                f16x8 xl = *(const f16x8*)(Rl + off);
                #pragma unroll
                for (int n = 0; n < 5; n++) {
                    if (n < NT) {
                        const f16* g2h = w2h + (rowoff + n*16 + l15)*64 + kc + quad*8;
                        const f16* g2l = w2l + (rowoff + n*16 + l15)*64 + kc + quad*8;
                        f16x8 bh = *(const f16x8*)g2h;
                        f16x8 bl = *(const f16x8*)g2l;
                        a2[n] = __builtin_amdgcn_mfma_f32_16x16x32_f16(xh, bh, a2[n], 0,0,0);
                        a2[n] = __builtin_amdgcn_mfma_f32_16x16x32_f16(xh, bl, a2[n], 0,0,0);
                        a2[n] = __builtin_amdgcn_mfma_f32_16x16x32_f16(xl, bh, a2[n], 0,0,0);
                    }
                }
            }
            const int pxg = 64*h + w*16 + quad*4;    // +rg
            if (br == 0) {
                #pragma unroll
                for (int n = 0; n < 5; n++) {
                    int co2 = n*16 + l15;
                    float bb = b2c[co2];
                    #pragma unroll
                    for (int rg = 0; rg < 4; rg++) {
                        float sv = a2[n][rg]*INV_ACC + bb;
                        cls_o[((size_t)(b*80 + co2)*128 + y)*128 + pxg + rg] = 1.f/(1.f + expf(-sv));
                    }
                }
            } else if (l15 < 2) {
                const float* b2 = (br == 1) ? b2r : b2w;
                float* outp     = (br == 1) ? reg_o : wh_o;
                float bb = b2[l15];
                #pragma unroll
                for (int rg = 0; rg < 4; rg++) {
                    float sv = a2[0][rg]*INV_ACC + bb;
                    float o  = (br == 1) ? (1.f/(1.f + expf(-sv))) : expf(sv);
                    outp[((size_t)(b*2 + l15))*HWSZ + y*128 + pxg + rg] = o;
                }
            }
        }
    }
}

// ---------------------------------------------------------------------------
// 3x3 peak mask + max/argmax over classes — barrier-free (r5, verified).
// ---------------------------------------------------------------------------
__global__ __launch_bounds__(256) void k_peaks(const float* __restrict__ cls,
                                               float* __restrict__ sc,
                                               int* __restrict__ cat) {
    const int b  = blockIdx.y;
    const int wv = threadIdx.x >> 6;
    const int l  = threadIdx.x & 63;
    const int y  = blockIdx.x * 4 + wv;
    const int p0 = l * 2;
    const bool yt = (y > 0), yb = (y < 127);
    float best0 = -1.f, best1 = -1.f;
    int bc0 = 0, bc1 = 0;
    for (int c = 0; c < 80; c++) {
        const float* pl = cls + (size_t)(b*80 + c)*HWSZ + y*128 + p0;
        float2 cur = *(const float2*)pl;
        float2 tp  = yt ? *(const float2*)(pl - 128) : make_float2(-1e30f, -1e30f);
        float2 bt  = yb ? *(const float2*)(pl + 128) : make_float2(-1e30f, -1e30f);
        float vm0 = fmaxf(cur.x, fmaxf(tp.x, bt.x));
        float vm1 = fmaxf(cur.y, fmaxf(tp.y, bt.y));
        float lft = __shfl_up(vm1, 1);   if (l == 0)  lft = -1e30f;
        float rgt = __shfl_down(vm0, 1); if (l == 63) rgt = -1e30f;
        float m0 = fmaxf(lft, fmaxf(vm0, vm1));
        float m1 = fmaxf(vm0, fmaxf(vm1, rgt));
        float k0 = (cur.x == m0) ? cur.x : 0.f;
        float k1 = (cur.y == m1) ? cur.y : 0.f;
        if (k0 > best0) { best0 = k0; bc0 = c; }   // strict > == first-max
        if (k1 > best1) { best1 = k1; bc1 = c; }
    }
    int o = b*HWSZ + y*128 + p0;
    *(float2*)&sc[o] = make_float2(best0, best1);
    *(int2*)&cat[o]  = make_int2(bc0, bc1);
}

// ---------------------------------------------------------------------------
// Fused per-batch top-100 + box decode + NMS + all outputs.
// r8: rescan is READ-ONLY (sc never written) with an LDS selected-bitmask —
// removes the global write->read dependency from the 100-iter serial chain.
// ---------------------------------------------------------------------------
__global__ void k_select(const float* __restrict__ sc, const int* __restrict__ cats,
                         const float* __restrict__ regp, const float* __restrict__ whp,
                         float* __restrict__ out) {
    const int b   = blockIdx.x;
    const int tid = threadIdx.x;
    const float* scb = sc + (size_t)b*HWSZ;

    __shared__ float cmax[64];
    __shared__ int   cidx[64];
    __shared__ uint  selmask[512];      // 16384 bits
    __shared__ int   s_inds[KK];
    __shared__ float s_vals[KK];
    __shared__ float X1[KK], Y1[KK], X2[KK], Y2[KK], AR[KK];

    selmask[tid] = 0u; selmask[tid + 256] = 0u;

    {   // Phase A: per-chunk max (value desc, first index)
        int c = tid >> 2, q = tid & 3;
        int base = c*256 + q*64;
        float bv = -1e30f; int bi = base;
        for (int e = 0; e < 64; e++) {
            float v = scb[base + e];
            if (v > bv) { bv = v; bi = base + e; }
        }
        #pragma unroll
        for (int off = 1; off <= 2; off <<= 1) {
            float ov = __shfl_xor(bv, off);
            int   oi = __shfl_xor(bi, off);
            if (ov > bv || (ov == bv && oi < bi)) { bv = ov; bi = oi; }
        }
        if (q == 0) { cmax[c] = bv; cidx[c] = bi; }
    }
    __syncthreads();

    if (tid < 64) {  // Phase B: 100 selections, wave 0
        const int l = tid;
        float v = cmax[l]; int ix = cidx[l];
        for (int it = 0; it < KK; it++) {
            float rv = v; int ri = ix;
            #pragma unroll
            for (int off = 32; off >= 1; off >>= 1) {
                float ov = __shfl_down(rv, off);
                int   oi = __shfl_down(ri, off);
                if (ov > rv || (ov == rv && oi < ri)) { rv = ov; ri = oi; }
            }
            float fv = __shfl(rv, 0);
            int   fi = __shfl(ri, 0);
            if (l == 0) {
                s_inds[it] = fi; s_vals[it] = fv;
                atomicOr(&selmask[fi >> 5], 1u << (fi & 31));
            }
            __threadfence_block();
            int wc = fi >> 8;
            int eb = wc*256 + l*4;
            uint mw = selmask[wc*8 + (l >> 3)];
            float nv = -1e30f; int ni = eb;
            #pragma unroll
            for (int r = 0; r < 4; r++) {
                float u = scb[eb + r];
                bool masked = (mw >> (((l & 7)*4 + r))) & 1u;
                if (!masked && u > nv) { nv = u; ni = eb + r; }
            }
            #pragma unroll
            for (int off = 32; off >= 1; off >>= 1) {
                float ov = __shfl_down(nv, off);
                int   oi = __shfl_down(ni, off);
                if (ov > nv || (ov == nv && oi < ni)) { nv = ov; ni = oi; }
            }
            float cv = __shfl(nv, 0);
            int   ci2 = __shfl(ni, 0);
            if (l == wc) { v = cv; ix = ci2; }
        }
    }
    __syncthreads();

    if (tid < KK) {  // Phase C: decode boxes
        int ind   = s_inds[tid];
        float scv = s_vals[tid];
        const float* rb = regp + (size_t)b*2*HWSZ;
        const float* wb = whp  + (size_t)b*2*HWSZ;
        float r0 = rb[ind], r1 = rb[HWSZ + ind];
        float w0 = wb[ind], w1 = wb[HWSZ + ind];
        float ctx = (float)(ind & 127) + r0;
        float cty = (float)(ind >> 7) + r1;
        float x1 = (ctx - w0*0.5f)*4.f, y1 = (cty - w1*0.5f)*4.f;
        float x2 = (ctx + w0*0.5f)*4.f, y2 = (cty + w1*0.5f)*4.f;
        size_t bo = ((size_t)b*KK + tid)*4;
        out[bo+0] = x1; out[bo+1] = y1; out[bo+2] = x2; out[bo+3] = y2;
        out[BN*KK*4 + b*KK + tid]         = (float)cats[(size_t)b*HWSZ + ind];
        out[BN*KK*4 + BN*KK + b*KK + tid] = scv;
        X1[tid] = x1; Y1[tid] = y1; X2[tid] = x2; Y2[tid] = y2;
        AR[tid] = (x2 - x1)*(y2 - y1);
    }
    __syncthreads();

    if (tid < 64) {  // Phase D: NMS in wave 0
        const int l = tid;
        float x1a = X1[l], y1a = Y1[l], x2a = X2[l], y2a = Y2[l], ara = AR[l];
        int   ka  = (s_vals[l] > 0.2f) ? 1 : 0;
        float x1b = 0, y1b = 0, x2b = 0, y2b = 0, arb = 0;
        int   kb  = 0;
        if (l < KK - 64) {
            x1b = X1[64+l]; y1b = Y1[64+l]; x2b = X2[64+l]; y2b = Y2[64+l];
            arb = AR[64+l];
            kb  = (s_vals[64+l] > 0.2f) ? 1 : 0;
        }
        for (int i = 0; i < KK; i++) {
            float jx1, jy1, jx2, jy2, jar; int jk;
            if (i < 64) {
                jx1 = __shfl(x1a, i); jy1 = __shfl(y1a, i);
                jx2 = __shfl(x2a, i); jy2 = __shfl(y2a, i);
                jar = __shfl(ara, i); jk  = __shfl(ka,  i);
            } else {
                int li = i - 64;
                jx1 = __shfl(x1b, li); jy1 = __shfl(y1b, li);
                jx2 = __shfl(x2b, li); jy2 = __shfl(y2b, li);
                jar = __shfl(arb, li); jk  = __shfl(kb,  li);
            }
            if (jk) {
                if (ka && l > i) {
                    float iw = fminf(jx2, x2a) - fmaxf(jx1, x1a); iw = iw > 0.f ? iw : 0.f;
                    float ih = fminf(jy2, y2a) - fmaxf(jy1, y1a); ih = ih > 0.f ? ih : 0.f;
                    float inter = iw*ih;
                    float iou = inter / (jar + ara - inter + 1e-9f);
                    if (iou > 0.5f) ka = 0;
                }
                if (kb && (64 + l) > i) {
                    float iw = fminf(jx2, x2b) - fmaxf(jx1, x1b); iw = iw > 0.f ? iw : 0.f;
                    float ih = fminf(jy2, y2b) - fmaxf(jy1, y1b); ih = ih > 0.f ? ih : 0.f;
                    float inter = iw*ih;
                    float iou = inter / (jar + arb - inter + 1e-9f);
                    if (iou > 0.5f) kb = 0;
                }
            }
        }
        int koff = BN*KK*4 + 2*BN*KK;
        out[koff + b*KK + l] = ka ? 1.f : 0.f;
        if (l < KK - 64) out[koff + b*KK + 64 + l] = kb ? 1.f : 0.f;
    }
}

// ---------------------------------------------------------------------------
extern "C" void kernel_launch(void* const* d_in, const int* in_sizes, int n_in,
                              void* d_out, int out_size, void* d_ws, size_t ws_size,
                              hipStream_t stream) {
    const float* x      = (const float*)d_in[0];
    const float* cls_w1 = (const float*)d_in[1];
    const float* cls_b1 = (const float*)d_in[2];
    const float* cls_w2 = (const float*)d_in[3];
    const float* cls_b2 = (const float*)d_in[4];
    const float* reg_w1 = (const float*)d_in[5];
    const float* reg_b1 = (const float*)d_in[6];
    const float* reg_w2 = (const float*)d_in[7];
    const float* reg_b2 = (const float*)d_in[8];
    const float* wh_w1  = (const float*)d_in[9];
    const float* wh_b1  = (const float*)d_in[10];
    const float* wh_w2  = (const float*)d_in[11];
    const float* wh_b2  = (const float*)d_in[12];

    float* ws   = (float*)d_ws;
    float* clsb = ws + WS_CLS;
    float* regb = ws + WS_REG;
    float* whb  = ws + WS_WH;
    float* scw  = ws + WS_SC;
    int*   cat  = (int*)(ws + WS_CAT);
    f16*   w1h  = (f16*)(ws + WS_W1H);
    f16*   w1l  = (f16*)(ws + WS_W1L);
    f16*   w2h  = (f16*)(ws + WS_W2H);
    f16*   w2l  = (f16*)(ws + WS_W2L);
    float* out  = (float*)d_out;

    k_prep<<<(3*9*64*64 + 112*64 + 255)/256, 256, 0, stream>>>(
        cls_w1, reg_w1, wh_w1, cls_w2, reg_w2, wh_w2, w1h, w1l, w2h, w2l);
    k_conv<<<dim3(128, 16), 256, 0, stream>>>(
        x, w1h, w1l, w2h, w2l, cls_b1, reg_b1, wh_b1,
        cls_b2, reg_b2, wh_b2, clsb, regb, whb);
    k_peaks<<<dim3(32, 16), 256, 0, stream>>>(clsb, scw, cat);
    k_select<<<16, 256, 0, stream>>>(scw, cat, regb, whb, out);
}

// Round 9
// 799.232 us; speedup vs baseline: 1.5218x; 1.5218x over previous
//
#include <hip/hip_runtime.h>
#include <math.h>

// Problem constants
#define BN 16
#define HWSZ 16384
#define NC 80
#define KK 100

typedef _Float16 f16;
typedef _Float16 f16x2 __attribute__((ext_vector_type(2)));
typedef _Float16 f16x4 __attribute__((ext_vector_type(4)));
typedef _Float16 f16x8 __attribute__((ext_vector_type(8)));
typedef float    f32x4 __attribute__((ext_vector_type(4)));
typedef unsigned int uint;

// ---- workspace layout (float units) ----
#define WS_CLS   0
#define CLS_SZ   (BN*NC*HWSZ)
#define WS_REG   (WS_CLS + CLS_SZ)
#define REG_SZ   (BN*2*HWSZ)
#define WS_WH    (WS_REG + REG_SZ)
#define WH_SZ    (BN*2*HWSZ)
#define WS_SC    (WS_WH + WH_SZ)
#define SC_SZ    (BN*HWSZ)
#define WS_CAT   (WS_SC + SC_SZ)
#define CAT_SZ   (BN*HWSZ)
#define WS_W1H   (WS_CAT + CAT_SZ)             // f16 3*9*64*64 -> 55296 floats/plane
#define W1F      (110592/2)
#define WS_W1L   (WS_W1H + W1F)
#define WS_W2H   (WS_W1L + W1F)                // f16 112*64 (padded) -> 3584 floats/plane
#define W2F      (7168/2)
#define WS_W2L   (WS_W2H + W2F)

// scaling: x*16, w*256 -> acc = 4096*true
#define SCL_X   16.0f
#define SCL_W   256.0f
#define INV_ACC (1.0f/4096.0f)

// ---------------------------------------------------------------------------
// Prep: split weights to fp16 hi/lo (scaled by 256).
// w1: [br][s=3dy+dx][co][ci].  w2 padded 112 rows: [0..79]=cls, [80..81]=reg,
// [96..97]=wh, rest 0.
// ---------------------------------------------------------------------------
__global__ void k_prep(const float* __restrict__ cw1, const float* __restrict__ rw1,
                       const float* __restrict__ ww1, const float* __restrict__ cw2,
                       const float* __restrict__ rw2, const float* __restrict__ ww2,
                       f16* __restrict__ w1h, f16* __restrict__ w1l,
                       f16* __restrict__ w2h, f16* __restrict__ w2l) {
    int idx = blockIdx.x * 256 + threadIdx.x;
    if (idx < 3*9*64*64) {
        int ci = idx & 63, co = (idx >> 6) & 63;
        int s  = (idx >> 12) % 9, br = idx / 36864;
        const float* src = (br == 0) ? cw1 : (br == 1 ? rw1 : ww1);
        float v = src[(co*64 + ci)*9 + s] * SCL_W;
        f16 h = (f16)v;
        w1h[idx] = h; w1l[idx] = (f16)(v - (float)h);
    }
    int j = idx - 3*9*64*64;
    if (j >= 0 && j < 112*64) {
        int ci = j & 63, row = j >> 6;
        float v = 0.f;
        if (row < 80)                    v = cw2[row*64 + ci];
        else if (row < 82)               v = rw2[(row-80)*64 + ci];
        else if (row >= 96 && row < 98)  v = ww2[(row-96)*64 + ci];
        v *= SCL_W;
        f16 h = (f16)v;
        w2h[j] = h; w2l[j] = (f16)(v - (float)h);
    }
}

// ---------------------------------------------------------------------------
// Fused MFMA conv. grid (y=128, b=16), block 256 (4 waves; wave w: px[32w,+32)).
// r8 post-mortem: half-pass epilogue blew arch VGPRs 96->196 (acc live across
// halves) -> 1 wave/SIMD. r9: keep r7's register-friendly epilogue verbatim;
// push the BRANCH loop inside the si loop instead (A-frags are br-invariant):
//  - A staged once, not 3x (stages 18->6, barriers ~42->18, FETCH 300->130MB)
//  - 216 MFMAs per barrier pair (was 72) -> 3x latency cover per drain
//  - acc[3][2][4] = 96 AGPRs; arch VGPRs stay ~100 -> 2 waves/SIMD holds
// Same MFMA term order as r7 -> bit-identical outputs.
// ---------------------------------------------------------------------------
#define A_STRIDE 36                  // f16 per px row (32 ci + pad)
#define AL_OFF   4680                // f16 offset of lo plane (130*36)
__global__ __launch_bounds__(256) void k_conv(
    const float* __restrict__ x,
    const f16* __restrict__ w1h, const f16* __restrict__ w1l,
    const f16* __restrict__ w2h, const f16* __restrict__ w2l,
    const float* __restrict__ b1c, const float* __restrict__ b1r, const float* __restrict__ b1w,
    const float* __restrict__ b2c, const float* __restrict__ b2r, const float* __restrict__ b2w,
    float* __restrict__ cls_o, float* __restrict__ reg_o, float* __restrict__ wh_o)
{
    __shared__ char smem[36864] __attribute__((aligned(16)));
    f16* AH = (f16*)smem;                 // [130][36] hi (conv1 phase)
    f16* AL = (f16*)smem + AL_OFF;        // [130][36] lo
    f16* Rh = (f16*)smem;                 // [128][72] hi (epilogue alias)
    f16* Rl = (f16*)(smem + 18432);       // [128][72] lo

    const int y = blockIdx.x, b = blockIdx.y;
    const int tid = threadIdx.x;
    const int w = tid >> 6, lane = tid & 63;
    const int l15 = lane & 15, quad = lane >> 4;
    const int wbase = w * 32;

    static const int CS[6] = {0,0,0,1,1,1};
    static const int RS[6] = {0,1,2,0,1,2};

    f32x4 acc[3][2][4];
    #pragma unroll
    for (int br = 0; br < 3; br++)
        #pragma unroll
        for (int m = 0; m < 2; m++)
            #pragma unroll
            for (int n = 0; n < 4; n++) acc[br][m][n] = (f32x4){0.f,0.f,0.f,0.f};

    // ======================= conv1: single pass, all branches =======================
    for (int si = 0; si < 6; si++) {
        __syncthreads();                 // prior compute on A done
        if (si == 0 && tid < 72) {       // zero px guard rows (slots 0,129), once
            int plane = tid / 36, rem = tid % 36;
            int row = (rem < 18) ? 0 : 129, wd = rem % 18;
            ((uint*)smem)[plane*(AL_OFF/2) + row*18 + wd] = 0u;
        }
        {   // stage input row gy, chunk: 32 ci x 128 px, hi/lo split
            const int gy = y - 1 + RS[si];
            const bool ok = (gy >= 0) && (gy < 128);
            const float* xp = x + ((size_t)(b*64 + CS[si]*32)*128 + gy)*128;
            f16x2* dh = (f16x2*)AH;
            f16x2* dl = (f16x2*)AL;
            #pragma unroll
            for (int e0 = 0; e0 < 2048; e0 += 256) {
                int e = e0 + tid;
                int px = e & 127, cp = e >> 7;
                float v0 = 0.f, v1 = 0.f;
                if (ok) { v0 = xp[(size_t)(2*cp)*HWSZ + px]*SCL_X;
                          v1 = xp[(size_t)(2*cp+1)*HWSZ + px]*SCL_X; }
                f16 h0 = (f16)v0, h1 = (f16)v1;
                f16 l0 = (f16)(v0 - (float)h0), l1 = (f16)(v1 - (float)h1);
                int wi = (px + 1)*(A_STRIDE/2) + cp;
                dh[wi] = (f16x2){h0, h1};
                dl[wi] = (f16x2){l0, l1};
            }
        }
        __syncthreads();
        const int chunk = CS[si], r = RS[si];
        #pragma unroll
        for (int dx = 0; dx < 3; dx++) {
            const int s = r*3 + dx;
            // A-fragments: branch-invariant, loaded once per dx
            f16x8 ah[2], al[2];
            #pragma unroll
            for (int m = 0; m < 2; m++) {
                int off = (wbase + m*16 + l15 + dx)*A_STRIDE + quad*8;
                f16x4 h0 = *(const f16x4*)(AH + off);
                f16x4 h1 = *(const f16x4*)(AH + off + 4);
                f16x4 u0 = *(const f16x4*)(AL + off);
                f16x4 u1 = *(const f16x4*)(AL + off + 4);
                ah[m] = __builtin_shufflevector(h0, h1, 0,1,2,3,4,5,6,7);
                al[m] = __builtin_shufflevector(u0, u1, 0,1,2,3,4,5,6,7);
            }
            #pragma unroll
            for (int br = 0; br < 3; br++) {
                const f16* gbh = w1h + ((size_t)((br*9 + s)*64 + l15))*64 + chunk*32 + quad*8;
                const f16* gbl = w1l + ((size_t)((br*9 + s)*64 + l15))*64 + chunk*32 + quad*8;
                #pragma unroll
                for (int n = 0; n < 4; n++) {
                    f16x8 bh = *(const f16x8*)(gbh + n*1024);
                    f16x8 bl = *(const f16x8*)(gbl + n*1024);
                    #pragma unroll
                    for (int m = 0; m < 2; m++) {
                        acc[br][m][n] = __builtin_amdgcn_mfma_f32_16x16x32_f16(ah[m], bh, acc[br][m][n], 0,0,0);
                        acc[br][m][n] = __builtin_amdgcn_mfma_f32_16x16x32_f16(ah[m], bl, acc[br][m][n], 0,0,0);
                        acc[br][m][n] = __builtin_amdgcn_mfma_f32_16x16x32_f16(al[m], bh, acc[br][m][n], 0,0,0);
                    }
                }
            }
        }
    }

    // ======================= epilogue per branch (r7 verbatim) =======================
    #pragma unroll
    for (int br = 0; br < 3; br++) {
        const float* b1 = (br == 0) ? b1c : (br == 1 ? b1r : b1w);
        float b1v[4];
        #pragma unroll
        for (int n = 0; n < 4; n++) b1v[n] = b1[n*16 + l15];
        __syncthreads();                 // prior A use / prior conv2 reads done
        #pragma unroll
        for (int m = 0; m < 2; m++)
            #pragma unroll
            for (int n = 0; n < 4; n++)
                #pragma unroll
                for (int rg = 0; rg < 4; rg++) {
                    float t = fmaxf(acc[br][m][n][rg]*INV_ACC + b1v[n], 0.f) * SCL_X;
                    f16 h = (f16)t;
                    int px = wbase + m*16 + quad*4 + rg;
                    int co = n*16 + l15;
                    Rh[px*72 + co] = h;
                    Rl[px*72 + co] = (f16)(t - (float)h);
                }
        __syncthreads();

        const int NT     = (br == 0) ? 5 : 1;
        const int rowoff = (br == 0) ? 0 : (br == 1 ? 80 : 96);
        f32x4 a2[5][2];
        #pragma unroll
        for (int n = 0; n < 5; n++)
            #pragma unroll
            for (int m = 0; m < 2; m++) a2[n][m] = (f32x4){0.f,0.f,0.f,0.f};

        #pragma unroll
        for (int kc = 0; kc < 64; kc += 32) {
            f16x8 xh[2], xl[2];
            #pragma unroll
            for (int m = 0; m < 2; m++) {
                int off = (wbase + m*16 + l15)*72 + kc + quad*8;
                f16x4 h0 = *(const f16x4*)(Rh + off);
                f16x4 h1 = *(const f16x4*)(Rh + off + 4);
                f16x4 u0 = *(const f16x4*)(Rl + off);
                f16x4 u1 = *(const f16x4*)(Rl + off + 4);
                xh[m] = __builtin_shufflevector(h0, h1, 0,1,2,3,4,5,6,7);
                xl[m] = __builtin_shufflevector(u0, u1, 0,1,2,3,4,5,6,7);
            }
            #pragma unroll
            for (int n = 0; n < 5; n++) {
                if (n >= NT) break;
                const f16* g2h = w2h + (rowoff + n*16 + l15)*64 + kc + quad*8;
                const f16* g2l = w2l + (rowoff + n*16 + l15)*64 + kc + quad*8;
                f16x8 bh = *(const f16x8*)g2h;
                f16x8 bl = *(const f16x8*)g2l;
                #pragma unroll
                for (int m = 0; m < 2; m++) {
                    a2[n][m] = __builtin_amdgcn_mfma_f32_16x16x32_f16(xh[m], bh, a2[n][m], 0,0,0);
                    a2[n][m] = __builtin_amdgcn_mfma_f32_16x16x32_f16(xh[m], bl, a2[n][m], 0,0,0);
                    a2[n][m] = __builtin_amdgcn_mfma_f32_16x16x32_f16(xl[m], bh, a2[n][m], 0,0,0);
                }
            }
        }

        if (br == 0) {
            #pragma unroll
            for (int n = 0; n < 5; n++) {
                int co2 = n*16 + l15;
                float bb = b2c[co2];
                #pragma unroll
                for (int m = 0; m < 2; m++)
                    #pragma unroll
                    for (int rg = 0; rg < 4; rg++) {
                        float sv = a2[n][m][rg]*INV_ACC + bb;
                        int px = wbase + m*16 + quad*4 + rg;
                        cls_o[((size_t)(b*80 + co2)*128 + y)*128 + px] = 1.f/(1.f + expf(-sv));
                    }
            }
        } else {
            if (l15 < 2) {
                const float* b2 = (br == 1) ? b2r : b2w;
                float* outp     = (br == 1) ? reg_o : wh_o;
                float bb = b2[l15];
                #pragma unroll
                for (int m = 0; m < 2; m++)
                    #pragma unroll
                    for (int rg = 0; rg < 4; rg++) {
                        float sv = a2[0][m][rg]*INV_ACC + bb;
                        float o  = (br == 1) ? (1.f/(1.f + expf(-sv))) : expf(sv);
                        int px = wbase + m*16 + quad*4 + rg;
                        outp[((size_t)(b*2 + l15)*128 + y)*128 + px] = o;
                    }
            }
        }
    }
}

// ---------------------------------------------------------------------------
// 3x3 peak mask + max/argmax over classes — barrier-free, 4 rows per wave.
// grid (8, 16), block 256 = 4 waves; wave wv: rows y0..y0+3, y0 = bx*16+wv*4.
// 6 row-loads per 4 output rows (1.5x redundancy vs r5's 3x).
// ---------------------------------------------------------------------------
__global__ __launch_bounds__(256) void k_peaks(const float* __restrict__ cls,
                                               float* __restrict__ sc,
                                               int* __restrict__ cat) {
    const int b  = blockIdx.y;
    const int wv = threadIdx.x >> 6;
    const int l  = threadIdx.x & 63;
    const int y0 = blockIdx.x * 16 + wv * 4;
    const int p0 = l * 2;
    float best0[4] = {-1.f,-1.f,-1.f,-1.f};
    float best1[4] = {-1.f,-1.f,-1.f,-1.f};
    int   bc0[4]   = {0,0,0,0};
    int   bc1[4]   = {0,0,0,0};
    for (int c = 0; c < 80; c++) {
        const float* pl = cls + (size_t)(b*80 + c)*HWSZ + p0;
        float2 row[6];
        #pragma unroll
        for (int r = 0; r < 6; r++) {
            int yy = y0 - 1 + r;
            row[r] = (yy >= 0 && yy < 128) ? *(const float2*)(pl + yy*128)
                                           : make_float2(-1e30f, -1e30f);
        }
        #pragma unroll
        for (int i = 0; i < 4; i++) {
            float vx = fmaxf(row[i].x, fmaxf(row[i+1].x, row[i+2].x));
            float vy = fmaxf(row[i].y, fmaxf(row[i+1].y, row[i+2].y));
            float lft = __shfl_up(vy, 1);   if (l == 0)  lft = -1e30f;
            float rgt = __shfl_down(vx, 1); if (l == 63) rgt = -1e30f;
            float m0 = fmaxf(lft, fmaxf(vx, vy));
            float m1 = fmaxf(vx, fmaxf(vy, rgt));
            float k0 = (row[i+1].x == m0) ? row[i+1].x : 0.f;
            float k1 = (row[i+1].y == m1) ? row[i+1].y : 0.f;
            if (k0 > best0[i]) { best0[i] = k0; bc0[i] = c; }  // strict > == first-max
            if (k1 > best1[i]) { best1[i] = k1; bc1[i] = c; }
        }
    }
    #pragma unroll
    for (int i = 0; i < 4; i++) {
        int o = b*HWSZ + (y0 + i)*128 + p0;
        *(float2*)&sc[o] = make_float2(best0[i], best1[i]);
        *(int2*)&cat[o]  = make_int2(bc0[i], bc1[i]);
    }
}

// ---------------------------------------------------------------------------
// Fused per-batch top-100 + box decode + NMS + all outputs (r8, verified).
// ---------------------------------------------------------------------------
__global__ void k_select(const float* __restrict__ sc, const int* __restrict__ cats,
                         const float* __restrict__ regp, const float* __restrict__ whp,
                         float* __restrict__ out) {
    const int b   = blockIdx.x;
    const int tid = threadIdx.x;
    const float* scb = sc + (size_t)b*HWSZ;

    __shared__ float cmax[64];
    __shared__ int   cidx[64];
    __shared__ uint  selmask[512];      // 16384 bits
    __shared__ int   s_inds[KK];
    __shared__ float s_vals[KK];
    __shared__ float X1[KK], Y1[KK], X2[KK], Y2[KK], AR[KK];

    selmask[tid] = 0u; selmask[tid + 256] = 0u;

    {   // Phase A: per-chunk max (value desc, first index)
        int c = tid >> 2, q = tid & 3;
        int base = c*256 + q*64;
        float bv = -1e30f; int bi = base;
        for (int e = 0; e < 64; e++) {
            float v = scb[base + e];
            if (v > bv) { bv = v; bi = base + e; }
        }
        #pragma unroll
        for (int off = 1; off <= 2; off <<= 1) {
            float ov = __shfl_xor(bv, off);
            int   oi = __shfl_xor(bi, off);
            if (ov > bv || (ov == bv && oi < bi)) { bv = ov; bi = oi; }
        }
        if (q == 0) { cmax[c] = bv; cidx[c] = bi; }
    }
    __syncthreads();

    if (tid < 64) {  // Phase B: 100 selections, wave 0
        const int l = tid;
        float v = cmax[l]; int ix = cidx[l];
        for (int it = 0; it < KK; it++) {
            float rv = v; int ri = ix;
            #pragma unroll
            for (int off = 32; off >= 1; off >>= 1) {
                float ov = __shfl_down(rv, off);
                int   oi = __shfl_down(ri, off);
                if (ov > rv || (ov == rv && oi < ri)) { rv = ov; ri = oi; }
            }
            float fv = __shfl(rv, 0);
            int   fi = __shfl(ri, 0);
            if (l == 0) {
                s_inds[it] = fi; s_vals[it] = fv;
                atomicOr(&selmask[fi >> 5], 1u << (fi & 31));
            }
            __threadfence_block();
            int wc = fi >> 8;
            int eb = wc*256 + l*4;
            uint mw = selmask[wc*8 + (l >> 3)];
            float nv = -1e30f; int ni = eb;
            #pragma unroll
            for (int r = 0; r < 4; r++) {
                float u = scb[eb + r];
                bool masked = (mw >> (((l & 7)*4 + r))) & 1u;
                if (!masked && u > nv) { nv = u; ni = eb + r; }
            }
            #pragma unroll
            for (int off = 32; off >= 1; off >>= 1) {
                float ov = __shfl_down(nv, off);
                int   oi = __shfl_down(ni, off);
                if (ov > nv || (ov == nv && oi < ni)) { nv = ov; ni = oi; }
            }
            float cv = __shfl(nv, 0);
            int   ci2 = __shfl(ni, 0);
            if (l == wc) { v = cv; ix = ci2; }
        }
    }
    __syncthreads();

    if (tid < KK) {  // Phase C: decode boxes
        int ind   = s_inds[tid];
        float scv = s_vals[tid];
        const float* rb = regp + (size_t)b*2*HWSZ;
        const float* wb = whp  + (size_t)b*2*HWSZ;
        float r0 = rb[ind], r1 = rb[HWSZ + ind];
        float w0 = wb[ind], w1 = wb[HWSZ + ind];
        float ctx = (float)(ind & 127) + r0;
        float cty = (float)(ind >> 7) + r1;
        float x1 = (ctx - w0*0.5f)*4.f, y1 = (cty - w1*0.5f)*4.f;
        float x2 = (ctx + w0*0.5f)*4.f, y2 = (cty + w1*0.5f)*4.f;
        size_t bo = ((size_t)b*KK + tid)*4;
        out[bo+0] = x1; out[bo+1] = y1; out[bo+2] = x2; out[bo+3] = y2;
        out[BN*KK*4 + b*KK + tid]         = (float)cats[(size_t)b*HWSZ + ind];
        out[BN*KK*4 + BN*KK + b*KK + tid] = scv;
        X1[tid] = x1; Y1[tid] = y1; X2[tid] = x2; Y2[tid] = y2;
        AR[tid] = (x2 - x1)*(y2 - y1);
    }
    __syncthreads();

    if (tid < 64) {  // Phase D: NMS in wave 0
        const int l = tid;
        float x1a = X1[l], y1a = Y1[l], x2a = X2[l], y2a = Y2[l], ara = AR[l];
        int   ka  = (s_vals[l] > 0.2f) ? 1 : 0;
        float x1b = 0, y1b = 0, x2b = 0, y2b = 0, arb = 0;
        int   kb  = 0;
        if (l < KK - 64) {
            x1b = X1[64+l]; y1b = Y1[64+l]; x2b = X2[64+l]; y2b = Y2[64+l];
            arb = AR[64+l];
            kb  = (s_vals[64+l] > 0.2f) ? 1 : 0;
        }
        for (int i = 0; i < KK; i++) {
            float jx1, jy1, jx2, jy2, jar; int jk;
            if (i < 64) {
                jx1 = __shfl(x1a, i); jy1 = __shfl(y1a, i);
                jx2 = __shfl(x2a, i); jy2 = __shfl(y2a, i);
                jar = __shfl(ara, i); jk  = __shfl(ka,  i);
            } else {
                int li = i - 64;
                jx1 = __shfl(x1b, li); jy1 = __shfl(y1b, li);
                jx2 = __shfl(x2b, li); jy2 = __shfl(y2b, li);
                jar = __shfl(arb, li); jk  = __shfl(kb,  li);
            }
            if (jk) {
                if (ka && l > i) {
                    float iw = fminf(jx2, x2a) - fmaxf(jx1, x1a); iw = iw > 0.f ? iw : 0.f;
                    float ih = fminf(jy2, y2a) - fmaxf(jy1, y1a); ih = ih > 0.f ? ih : 0.f;
                    float inter = iw*ih;
                    float iou = inter / (jar + ara - inter + 1e-9f);
                    if (iou > 0.5f) ka = 0;
                }
                if (kb && (64 + l) > i) {
                    float iw = fminf(jx2, x2b) - fmaxf(jx1, x1b); iw = iw > 0.f ? iw : 0.f;
                    float ih = fminf(jy2, y2b) - fmaxf(jy1, y1b); ih = ih > 0.f ? ih : 0.f;
                    float inter = iw*ih;
                    float iou = inter / (jar + arb - inter + 1e-9f);
                    if (iou > 0.5f) kb = 0;
                }
            }
        }
        int koff = BN*KK*4 + 2*BN*KK;
        out[koff + b*KK + l] = ka ? 1.f : 0.f;
        if (l < KK - 64) out[koff + b*KK + 64 + l] = kb ? 1.f : 0.f;
    }
}

// ---------------------------------------------------------------------------
extern "C" void kernel_launch(void* const* d_in, const int* in_sizes, int n_in,
                              void* d_out, int out_size, void* d_ws, size_t ws_size,
                              hipStream_t stream) {
    const float* x      = (const float*)d_in[0];
    const float* cls_w1 = (const float*)d_in[1];
    const float* cls_b1 = (const float*)d_in[2];
    const float* cls_w2 = (const float*)d_in[3];
    const float* cls_b2 = (const float*)d_in[4];
    const float* reg_w1 = (const float*)d_in[5];
    const float* reg_b1 = (const float*)d_in[6];
    const float* reg_w2 = (const float*)d_in[7];
    const float* reg_b2 = (const float*)d_in[8];
    const float* wh_w1  = (const float*)d_in[9];
    const float* wh_b1  = (const float*)d_in[10];
    const float* wh_w2  = (const float*)d_in[11];
    const float* wh_b2  = (const float*)d_in[12];

    float* ws   = (float*)d_ws;
    float* clsb = ws + WS_CLS;
    float* regb = ws + WS_REG;
    float* whb  = ws + WS_WH;
    float* scw  = ws + WS_SC;
    int*   cat  = (int*)(ws + WS_CAT);
    f16*   w1h  = (f16*)(ws + WS_W1H);
    f16*   w1l  = (f16*)(ws + WS_W1L);
    f16*   w2h  = (f16*)(ws + WS_W2H);
    f16*   w2l  = (f16*)(ws + WS_W2L);
    float* out  = (float*)d_out;

    k_prep<<<(3*9*64*64 + 112*64 + 255)/256, 256, 0, stream>>>(
        cls_w1, reg_w1, wh_w1, cls_w2, reg_w2, wh_w2, w1h, w1l, w2h, w2l);
    k_conv<<<dim3(128, 16), 256, 0, stream>>>(
        x, w1h, w1l, w2h, w2l, cls_b1, reg_b1, wh_b1,
        cls_b2, reg_b2, wh_b2, clsb, regb, whb);
    k_peaks<<<dim3(8, 16), 256, 0, stream>>>(clsb, scw, cat);
    k_select<<<16, 256, 0, stream>>>(scw, cat, regb, whb, out);
}

// Round 10
// 676.610 us; speedup vs baseline: 1.7976x; 1.1812x over previous
//
#include <hip/hip_runtime.h>
#include <math.h>

// Problem constants
#define BN 16
#define HWSZ 16384
#define NC 80
#define KK 100

typedef _Float16 f16;
typedef _Float16 f16x2 __attribute__((ext_vector_type(2)));
typedef _Float16 f16x4 __attribute__((ext_vector_type(4)));
typedef _Float16 f16x8 __attribute__((ext_vector_type(8)));
typedef float    f32x4 __attribute__((ext_vector_type(4)));
typedef unsigned int uint;

// ---- workspace layout (float units) ----
#define WS_CLS   0
#define CLS_SZ   (BN*NC*HWSZ)
#define WS_REG   (WS_CLS + CLS_SZ)
#define REG_SZ   (BN*2*HWSZ)
#define WS_WH    (WS_REG + REG_SZ)
#define WH_SZ    (BN*2*HWSZ)
#define WS_SC    (WS_WH + WH_SZ)
#define SC_SZ    (BN*HWSZ)
#define WS_CAT   (WS_SC + SC_SZ)
#define CAT_SZ   (BN*HWSZ)
#define WS_W1H   (WS_CAT + CAT_SZ)             // f16 3*9*64*64 -> 55296 floats/plane
#define W1F      (110592/2)
#define WS_W1L   (WS_W1H + W1F)
#define WS_W2H   (WS_W1L + W1F)                // f16 112*64 (padded) -> 3584 floats/plane
#define W2F      (7168/2)
#define WS_W2L   (WS_W2H + W2F)

// scaling: x*16, w*256 -> acc = 4096*true
#define SCL_X   16.0f
#define SCL_W   256.0f
#define INV_ACC (1.0f/4096.0f)

// ---------------------------------------------------------------------------
// Prep: split weights to fp16 hi/lo (scaled by 256).
// w1: [br][s=3dy+dx][co][ci].  w2 padded 112 rows: [0..79]=cls, [80..81]=reg,
// [96..97]=wh, rest 0.
// ---------------------------------------------------------------------------
__global__ void k_prep(const float* __restrict__ cw1, const float* __restrict__ rw1,
                       const float* __restrict__ ww1, const float* __restrict__ cw2,
                       const float* __restrict__ rw2, const float* __restrict__ ww2,
                       f16* __restrict__ w1h, f16* __restrict__ w1l,
                       f16* __restrict__ w2h, f16* __restrict__ w2l) {
    int idx = blockIdx.x * 256 + threadIdx.x;
    if (idx < 3*9*64*64) {
        int ci = idx & 63, co = (idx >> 6) & 63;
        int s  = (idx >> 12) % 9, br = idx / 36864;
        const float* src = (br == 0) ? cw1 : (br == 1 ? rw1 : ww1);
        float v = src[(co*64 + ci)*9 + s] * SCL_W;
        f16 h = (f16)v;
        w1h[idx] = h; w1l[idx] = (f16)(v - (float)h);
    }
    int j = idx - 3*9*64*64;
    if (j >= 0 && j < 112*64) {
        int ci = j & 63, row = j >> 6;
        float v = 0.f;
        if (row < 80)                    v = cw2[row*64 + ci];
        else if (row < 82)               v = rw2[(row-80)*64 + ci];
        else if (row >= 96 && row < 98)  v = ww2[(row-96)*64 + ci];
        v *= SCL_W;
        f16 h = (f16)v;
        w2h[j] = h; w2l[j] = (f16)(v - (float)h);
    }
}

// ---------------------------------------------------------------------------
// Fused MFMA conv. grid (y=128, b=16), block 256 (4 waves).
// r9 post-mortem: wave->m-tile mapping loads 432 KB of B frags per wave
// (3.5 GB/dispatch from L2), each B pair feeding only 6 MFMAs -> B latency
// exposed. r10: wave->N-TILE mapping: wave w owns co[16w,16w+16) for ALL
// 128 px (m=0..7). B frags/wave drop 4x (each pair feeds 24 MFMAs); A frags
// come from LDS. acc[3][8] = 96 AGPRs (same budget). Double-buffered A
// staging: 1 barrier/stage, staging global loads overlap compute in-wave.
// Accumulation order per acc element unchanged -> bit-identical outputs.
// ---------------------------------------------------------------------------
#define A_STRIDE 36                  // f16 per px row (32 ci + pad)
#define ABUF     18720               // bytes per A buffer (2 planes x 130 x 36 x 2B)
#define APLANEW  2340                // uint words per plane (9360 B)
__global__ __launch_bounds__(256) void k_conv(
    const float* __restrict__ x,
    const f16* __restrict__ w1h, const f16* __restrict__ w1l,
    const f16* __restrict__ w2h, const f16* __restrict__ w2l,
    const float* __restrict__ b1c, const float* __restrict__ b1r, const float* __restrict__ b1w,
    const float* __restrict__ b2c, const float* __restrict__ b2r, const float* __restrict__ b2w,
    float* __restrict__ cls_o, float* __restrict__ reg_o, float* __restrict__ wh_o)
{
    __shared__ char smem[37440] __attribute__((aligned(16)));
    f16* Rh = (f16*)smem;                 // [128][72] hi (epilogue alias)
    f16* Rl = (f16*)(smem + 18432);       // [128][72] lo

    const int y = blockIdx.x, b = blockIdx.y;
    const int tid = threadIdx.x;
    const int w = tid >> 6, lane = tid & 63;
    const int l15 = lane & 15, quad = lane >> 4;
    const int wbase = w * 32;             // conv2 epilogue mapping (r9 verbatim)

    static const int CS[6] = {0,0,0,1,1,1};
    static const int RS[6] = {0,1,2,0,1,2};

    #define STAGE(bufi, si_) do {                                             \
        const int gy = y - 1 + RS[si_];                                       \
        const bool ok = (gy >= 0) && (gy < 128);                              \
        const float* xp = x + ((size_t)(b*64 + CS[si_]*32)*128 + gy)*128;     \
        f16x2* dh = (f16x2*)(smem + (bufi)*ABUF);                             \
        f16x2* dl = (f16x2*)(smem + (bufi)*ABUF + 9360);                      \
        _Pragma("unroll")                                                     \
        for (int e0 = 0; e0 < 2048; e0 += 256) {                              \
            int e = e0 + tid;                                                 \
            int px = e & 127, cp = e >> 7;                                    \
            float v0 = 0.f, v1 = 0.f;                                         \
            if (ok) { v0 = xp[(size_t)(2*cp)*HWSZ + px]*SCL_X;                \
                      v1 = xp[(size_t)(2*cp+1)*HWSZ + px]*SCL_X; }            \
            f16 h0 = (f16)v0, h1 = (f16)v1;                                   \
            f16 l0 = (f16)(v0 - (float)h0), l1 = (f16)(v1 - (float)h1);       \
            int wi = (px + 1)*(A_STRIDE/2) + cp;                              \
            dh[wi] = (f16x2){h0, h1};                                         \
            dl[wi] = (f16x2){l0, l1};                                         \
        }                                                                     \
    } while (0)

    f32x4 acc[3][8];
    #pragma unroll
    for (int br = 0; br < 3; br++)
        #pragma unroll
        for (int m = 0; m < 8; m++) acc[br][m] = (f32x4){0.f,0.f,0.f,0.f};

    // zero px guard rows (slots 0,129) of all 4 planes (2 bufs x hi/lo), once
    if (tid < 144) {
        int plane = tid / 36, rem = tid % 36;
        int row = (rem < 18) ? 0 : 129, wd = rem % 18;
        ((uint*)smem)[plane*APLANEW + row*18 + wd] = 0u;
    }
    STAGE(0, 0);
    __syncthreads();

    // ======================= conv1: single pass, all branches =======================
    for (int si = 0; si < 6; si++) {
        const int cur = si & 1;
        if (si < 5) STAGE(cur ^ 1, si + 1);     // overlaps compute below
        const f16* APh = (const f16*)(smem + cur*ABUF);
        const f16* APl = APh + 4680;
        const int chunk = CS[si], r = RS[si];
        #pragma unroll
        for (int dx = 0; dx < 3; dx++) {
            const int s = r*3 + dx;
            // B fragments: wave w's co-tile, all 3 branches (6 loads -> 72 MFMAs)
            f16x8 bh[3], bl[3];
            #pragma unroll
            for (int br = 0; br < 3; br++) {
                size_t k = ((size_t)((br*9 + s)*64 + (w*16 + l15)))*64 + chunk*32 + quad*8;
                bh[br] = *(const f16x8*)(w1h + k);
                bl[br] = *(const f16x8*)(w1l + k);
            }
            #pragma unroll
            for (int m = 0; m < 8; m++) {
                int off = (m*16 + l15 + dx)*A_STRIDE + quad*8;
                f16x4 h0 = *(const f16x4*)(APh + off);
                f16x4 h1 = *(const f16x4*)(APh + off + 4);
                f16x4 u0 = *(const f16x4*)(APl + off);
                f16x4 u1 = *(const f16x4*)(APl + off + 4);
                f16x8 ah = __builtin_shufflevector(h0, h1, 0,1,2,3,4,5,6,7);
                f16x8 al = __builtin_shufflevector(u0, u1, 0,1,2,3,4,5,6,7);
                #pragma unroll
                for (int br = 0; br < 3; br++) {
                    acc[br][m] = __builtin_amdgcn_mfma_f32_16x16x32_f16(ah, bh[br], acc[br][m], 0,0,0);
                    acc[br][m] = __builtin_amdgcn_mfma_f32_16x16x32_f16(ah, bl[br], acc[br][m], 0,0,0);
                    acc[br][m] = __builtin_amdgcn_mfma_f32_16x16x32_f16(al, bh[br], acc[br][m], 0,0,0);
                }
            }
        }
        __syncthreads();   // staging of cur^1 visible; all reads of cur done
    }
    #undef STAGE

    // ======================= epilogue per branch =======================
    #pragma unroll
    for (int br = 0; br < 3; br++) {
        const float* b1 = (br == 0) ? b1c : (br == 1 ? b1r : b1w);
        const float b1v = b1[w*16 + l15];
        __syncthreads();                 // prior A use / prior conv2 reads done
        // R write: C layout (px = m*16+quad*4+rg, co = w*16+l15) -> A layout
        #pragma unroll
        for (int m = 0; m < 8; m++)
            #pragma unroll
            for (int rg = 0; rg < 4; rg++) {
                float t = fmaxf(acc[br][m][rg]*INV_ACC + b1v, 0.f) * SCL_X;
                f16 h = (f16)t;
                int px = m*16 + quad*4 + rg;
                int co = w*16 + l15;
                Rh[px*72 + co] = h;
                Rl[px*72 + co] = (f16)(t - (float)h);
            }
        __syncthreads();

        const int NT     = (br == 0) ? 5 : 1;
        const int rowoff = (br == 0) ? 0 : (br == 1 ? 80 : 96);
        f32x4 a2[5][2];
        #pragma unroll
        for (int n = 0; n < 5; n++)
            #pragma unroll
            for (int m = 0; m < 2; m++) a2[n][m] = (f32x4){0.f,0.f,0.f,0.f};

        #pragma unroll
        for (int kc = 0; kc < 64; kc += 32) {
            f16x8 xh[2], xl[2];
            #pragma unroll
            for (int m = 0; m < 2; m++) {
                int off = (wbase + m*16 + l15)*72 + kc + quad*8;
                f16x4 h0 = *(const f16x4*)(Rh + off);
                f16x4 h1 = *(const f16x4*)(Rh + off + 4);
                f16x4 u0 = *(const f16x4*)(Rl + off);
                f16x4 u1 = *(const f16x4*)(Rl + off + 4);
                xh[m] = __builtin_shufflevector(h0, h1, 0,1,2,3,4,5,6,7);
                xl[m] = __builtin_shufflevector(u0, u1, 0,1,2,3,4,5,6,7);
            }
            #pragma unroll
            for (int n = 0; n < 5; n++) {
                if (n >= NT) break;
                const f16* g2h = w2h + (rowoff + n*16 + l15)*64 + kc + quad*8;
                const f16* g2l = w2l + (rowoff + n*16 + l15)*64 + kc + quad*8;
                f16x8 bh = *(const f16x8*)g2h;
                f16x8 bl = *(const f16x8*)g2l;
                #pragma unroll
                for (int m = 0; m < 2; m++) {
                    a2[n][m] = __builtin_amdgcn_mfma_f32_16x16x32_f16(xh[m], bh, a2[n][m], 0,0,0);
                    a2[n][m] = __builtin_amdgcn_mfma_f32_16x16x32_f16(xh[m], bl, a2[n][m], 0,0,0);
                    a2[n][m] = __builtin_amdgcn_mfma_f32_16x16x32_f16(xl[m], bh, a2[n][m], 0,0,0);
                }
            }
        }

        if (br == 0) {
            #pragma unroll
            for (int n = 0; n < 5; n++) {
                int co2 = n*16 + l15;
                float bb = b2c[co2];
                #pragma unroll
                for (int m = 0; m < 2; m++)
                    #pragma unroll
                    for (int rg = 0; rg < 4; rg++) {
                        float sv = a2[n][m][rg]*INV_ACC + bb;
                        int px = wbase + m*16 + quad*4 + rg;
                        cls_o[((size_t)(b*80 + co2)*128 + y)*128 + px] = 1.f/(1.f + expf(-sv));
                    }
            }
        } else {
            if (l15 < 2) {
                const float* b2 = (br == 1) ? b2r : b2w;
                float* outp     = (br == 1) ? reg_o : wh_o;
                float bb = b2[l15];
                #pragma unroll
                for (int m = 0; m < 2; m++)
                    #pragma unroll
                    for (int rg = 0; rg < 4; rg++) {
                        float sv = a2[0][m][rg]*INV_ACC + bb;
                        float o  = (br == 1) ? (1.f/(1.f + expf(-sv))) : expf(sv);
                        int px = wbase + m*16 + quad*4 + rg;
                        outp[((size_t)(b*2 + l15)*128 + y)*128 + px] = o;
                    }
            }
        }
    }
}

// ---------------------------------------------------------------------------
// 3x3 peak mask + max/argmax over classes — barrier-free (r5 config: 1 row
// per wave, 512 blocks; r9's 4-row/128-block variant was TLP-starved, +27us).
// ---------------------------------------------------------------------------
__global__ __launch_bounds__(256) void k_peaks(const float* __restrict__ cls,
                                               float* __restrict__ sc,
                                               int* __restrict__ cat) {
    const int b  = blockIdx.y;
    const int wv = threadIdx.x >> 6;
    const int l  = threadIdx.x & 63;
    const int y  = blockIdx.x * 4 + wv;
    const int p0 = l * 2;
    const bool yt = (y > 0), yb = (y < 127);
    float best0 = -1.f, best1 = -1.f;
    int bc0 = 0, bc1 = 0;
    for (int c = 0; c < 80; c++) {
        const float* pl = cls + (size_t)(b*80 + c)*HWSZ + y*128 + p0;
        float2 cur = *(const float2*)pl;
        float2 tp  = yt ? *(const float2*)(pl - 128) : make_float2(-1e30f, -1e30f);
        float2 bt  = yb ? *(const float2*)(pl + 128) : make_float2(-1e30f, -1e30f);
        float vm0 = fmaxf(cur.x, fmaxf(tp.x, bt.x));
        float vm1 = fmaxf(cur.y, fmaxf(tp.y, bt.y));
        float lft = __shfl_up(vm1, 1);   if (l == 0)  lft = -1e30f;
        float rgt = __shfl_down(vm0, 1); if (l == 63) rgt = -1e30f;
        float m0 = fmaxf(lft, fmaxf(vm0, vm1));
        float m1 = fmaxf(vm0, fmaxf(vm1, rgt));
        float k0 = (cur.x == m0) ? cur.x : 0.f;
        float k1 = (cur.y == m1) ? cur.y : 0.f;
        if (k0 > best0) { best0 = k0; bc0 = c; }   // strict > == first-max
        if (k1 > best1) { best1 = k1; bc1 = c; }
    }
    int o = b*HWSZ + y*128 + p0;
    *(float2*)&sc[o] = make_float2(best0, best1);
    *(int2*)&cat[o]  = make_int2(bc0, bc1);
}

// ---------------------------------------------------------------------------
// Fused per-batch top-100 + box decode + NMS + all outputs (r8, verified).
// ---------------------------------------------------------------------------
__global__ void k_select(const float* __restrict__ sc, const int* __restrict__ cats,
                         const float* __restrict__ regp, const float* __restrict__ whp,
                         float* __restrict__ out) {
    const int b   = blockIdx.x;
    const int tid = threadIdx.x;
    const float* scb = sc + (size_t)b*HWSZ;

    __shared__ float cmax[64];
    __shared__ int   cidx[64];
    __shared__ uint  selmask[512];      // 16384 bits
    __shared__ int   s_inds[KK];
    __shared__ float s_vals[KK];
    __shared__ float X1[KK], Y1[KK], X2[KK], Y2[KK], AR[KK];

    selmask[tid] = 0u; selmask[tid + 256] = 0u;

    {   // Phase A: per-chunk max (value desc, first index)
        int c = tid >> 2, q = tid & 3;
        int base = c*256 + q*64;
        float bv = -1e30f; int bi = base;
        for (int e = 0; e < 64; e++) {
            float v = scb[base + e];
            if (v > bv) { bv = v; bi = base + e; }
        }
        #pragma unroll
        for (int off = 1; off <= 2; off <<= 1) {
            float ov = __shfl_xor(bv, off);
            int   oi = __shfl_xor(bi, off);
            if (ov > bv || (ov == bv && oi < bi)) { bv = ov; bi = oi; }
        }
        if (q == 0) { cmax[c] = bv; cidx[c] = bi; }
    }
    __syncthreads();

    if (tid < 64) {  // Phase B: 100 selections, wave 0
        const int l = tid;
        float v = cmax[l]; int ix = cidx[l];
        for (int it = 0; it < KK; it++) {
            float rv = v; int ri = ix;
            #pragma unroll
            for (int off = 32; off >= 1; off >>= 1) {
                float ov = __shfl_down(rv, off);
                int   oi = __shfl_down(ri, off);
                if (ov > rv || (ov == rv && oi < ri)) { rv = ov; ri = oi; }
            }
            float fv = __shfl(rv, 0);
            int   fi = __shfl(ri, 0);
            if (l == 0) {
                s_inds[it] = fi; s_vals[it] = fv;
                atomicOr(&selmask[fi >> 5], 1u << (fi & 31));
            }
            __threadfence_block();
            int wc = fi >> 8;
            int eb = wc*256 + l*4;
            uint mw = selmask[wc*8 + (l >> 3)];
            float nv = -1e30f; int ni = eb;
            #pragma unroll
            for (int r = 0; r < 4; r++) {
                float u = scb[eb + r];
                bool masked = (mw >> (((l & 7)*4 + r))) & 1u;
                if (!masked && u > nv) { nv = u; ni = eb + r; }
            }
            #pragma unroll
            for (int off = 32; off >= 1; off >>= 1) {
                float ov = __shfl_down(nv, off);
                int   oi = __shfl_down(ni, off);
                if (ov > nv || (ov == nv && oi < ni)) { nv = ov; ni = oi; }
            }
            float cv = __shfl(nv, 0);
            int   ci2 = __shfl(ni, 0);
            if (l == wc) { v = cv; ix = ci2; }
        }
    }
    __syncthreads();

    if (tid < KK) {  // Phase C: decode boxes
        int ind   = s_inds[tid];
        float scv = s_vals[tid];
        const float* rb = regp + (size_t)b*2*HWSZ;
        const float* wb = whp  + (size_t)b*2*HWSZ;
        float r0 = rb[ind], r1 = rb[HWSZ + ind];
        float w0 = wb[ind], w1 = wb[HWSZ + ind];
        float ctx = (float)(ind & 127) + r0;
        float cty = (float)(ind >> 7) + r1;
        float x1 = (ctx - w0*0.5f)*4.f, y1 = (cty - w1*0.5f)*4.f;
        float x2 = (ctx + w0*0.5f)*4.f, y2 = (cty + w1*0.5f)*4.f;
        size_t bo = ((size_t)b*KK + tid)*4;
        out[bo+0] = x1; out[bo+1] = y1; out[bo+2] = x2; out[bo+3] = y2;
        out[BN*KK*4 + b*KK + tid]         = (float)cats[(size_t)b*HWSZ + ind];
        out[BN*KK*4 + BN*KK + b*KK + tid] = scv;
        X1[tid] = x1; Y1[tid] = y1; X2[tid] = x2; Y2[tid] = y2;
        AR[tid] = (x2 - x1)*(y2 - y1);
    }
    __syncthreads();

    if (tid < 64) {  // Phase D: NMS in wave 0
        const int l = tid;
        float x1a = X1[l], y1a = Y1[l], x2a = X2[l], y2a = Y2[l], ara = AR[l];
        int   ka  = (s_vals[l] > 0.2f) ? 1 : 0;
        float x1b = 0, y1b = 0, x2b = 0, y2b = 0, arb = 0;
        int   kb  = 0;
        if (l < KK - 64) {
            x1b = X1[64+l]; y1b = Y1[64+l]; x2b = X2[64+l]; y2b = Y2[64+l];
            arb = AR[64+l];
            kb  = (s_vals[64+l] > 0.2f) ? 1 : 0;
        }
        for (int i = 0; i < KK; i++) {
            float jx1, jy1, jx2, jy2, jar; int jk;
            if (i < 64) {
                jx1 = __shfl(x1a, i); jy1 = __shfl(y1a, i);
                jx2 = __shfl(x2a, i); jy2 = __shfl(y2a, i);
                jar = __shfl(ara, i); jk  = __shfl(ka,  i);
            } else {
                int li = i - 64;
                jx1 = __shfl(x1b, li); jy1 = __shfl(y1b, li);
                jx2 = __shfl(x2b, li); jy2 = __shfl(y2b, li);
                jar = __shfl(arb, li); jk  = __shfl(kb,  li);
            }
            if (jk) {
                if (ka && l > i) {
                    float iw = fminf(jx2, x2a) - fmaxf(jx1, x1a); iw = iw > 0.f ? iw : 0.f;
                    float ih = fminf(jy2, y2a) - fmaxf(jy1, y1a); ih = ih > 0.f ? ih : 0.f;
                    float inter = iw*ih;
                    float iou = inter / (jar + ara - inter + 1e-9f);
                    if (iou > 0.5f) ka = 0;
                }
                if (kb && (64 + l) > i) {
                    float iw = fminf(jx2, x2b) - fmaxf(jx1, x1b); iw = iw > 0.f ? iw : 0.f;
                    float ih = fminf(jy2, y2b) - fmaxf(jy1, y1b); ih = ih > 0.f ? ih : 0.f;
                    float inter = iw*ih;
                    float iou = inter / (jar + arb - inter + 1e-9f);
                    if (iou > 0.5f) kb = 0;
                }
            }
        }
        int koff = BN*KK*4 + 2*BN*KK;
        out[koff + b*KK + l] = ka ? 1.f : 0.f;
        if (l < KK - 64) out[koff + b*KK + 64 + l] = kb ? 1.f : 0.f;
    }
}

// ---------------------------------------------------------------------------
extern "C" void kernel_launch(void* const* d_in, const int* in_sizes, int n_in,
                              void* d_out, int out_size, void* d_ws, size_t ws_size,
                              hipStream_t stream) {
    const float* x      = (const float*)d_in[0];
    const float* cls_w1 = (const float*)d_in[1];
    const float* cls_b1 = (const float*)d_in[2];
    const float* cls_w2 = (const float*)d_in[3];
    const float* cls_b2 = (const float*)d_in[4];
    const float* reg_w1 = (const float*)d_in[5];
    const float* reg_b1 = (const float*)d_in[6];
    const float* reg_w2 = (const float*)d_in[7];
    const float* reg_b2 = (const float*)d_in[8];
    const float* wh_w1  = (const float*)d_in[9];
    const float* wh_b1  = (const float*)d_in[10];
    const float* wh_w2  = (const float*)d_in[11];
    const float* wh_b2  = (const float*)d_in[12];

    float* ws   = (float*)d_ws;
    float* clsb = ws + WS_CLS;
    float* regb = ws + WS_REG;
    float* whb  = ws + WS_WH;
    float* scw  = ws + WS_SC;
    int*   cat  = (int*)(ws + WS_CAT);
    f16*   w1h  = (f16*)(ws + WS_W1H);
    f16*   w1l  = (f16*)(ws + WS_W1L);
    f16*   w2h  = (f16*)(ws + WS_W2H);
    f16*   w2l  = (f16*)(ws + WS_W2L);
    float* out  = (float*)d_out;

    k_prep<<<(3*9*64*64 + 112*64 + 255)/256, 256, 0, stream>>>(
        cls_w1, reg_w1, wh_w1, cls_w2, reg_w2, wh_w2, w1h, w1l, w2h, w2l);
    k_conv<<<dim3(128, 16), 256, 0, stream>>>(
        x, w1h, w1l, w2h, w2l, cls_b1, reg_b1, wh_b1,
        cls_b2, reg_b2, wh_b2, clsb, regb, whb);
    k_peaks<<<dim3(32, 16), 256, 0, stream>>>(clsb, scw, cat);
    k_select<<<16, 256, 0, stream>>>(scw, cat, regb, whb, out);
}

// Round 11
// 607.314 us; speedup vs baseline: 2.0027x; 1.1141x over previous
//
#include <hip/hip_runtime.h>
#include <math.h>

// Problem constants
#define BN 16
#define HWSZ 16384
#define NC 80
#define KK 100

typedef _Float16 f16;
typedef _Float16 f16x2 __attribute__((ext_vector_type(2)));
typedef _Float16 f16x4 __attribute__((ext_vector_type(4)));
typedef _Float16 f16x8 __attribute__((ext_vector_type(8)));
typedef float    f32x4 __attribute__((ext_vector_type(4)));
typedef unsigned int uint;

// ---- workspace layout (float units) ----
#define WS_CLS   0
#define CLS_SZ   (BN*NC*HWSZ)
#define WS_REG   (WS_CLS + CLS_SZ)
#define REG_SZ   (BN*2*HWSZ)
#define WS_WH    (WS_REG + REG_SZ)
#define WH_SZ    (BN*2*HWSZ)
#define WS_SC    (WS_WH + WH_SZ)
#define SC_SZ    (BN*HWSZ)
#define WS_CAT   (WS_SC + SC_SZ)
#define CAT_SZ   (BN*HWSZ)
#define WS_W1H   (WS_CAT + CAT_SZ)             // f16 3*9*64*64 -> 55296 floats/plane
#define W1F      (110592/2)
#define WS_W1L   (WS_W1H + W1F)
#define WS_W2H   (WS_W1L + W1F)                // f16 112*64 (padded) -> 3584 floats/plane
#define W2F      (7168/2)
#define WS_W2L   (WS_W2H + W2F)

// scaling: x*16, w*256 -> acc = 4096*true
#define SCL_X   16.0f
#define SCL_W   256.0f
#define INV_ACC (1.0f/4096.0f)

// ---------------------------------------------------------------------------
// Prep: split weights to fp16 hi/lo (scaled by 256).
// w1: [br][s=3dy+dx][co][ci].  w2 padded 112 rows: [0..79]=cls, [80..81]=reg,
// [96..97]=wh, rest 0.
// ---------------------------------------------------------------------------
__global__ void k_prep(const float* __restrict__ cw1, const float* __restrict__ rw1,
                       const float* __restrict__ ww1, const float* __restrict__ cw2,
                       const float* __restrict__ rw2, const float* __restrict__ ww2,
                       f16* __restrict__ w1h, f16* __restrict__ w1l,
                       f16* __restrict__ w2h, f16* __restrict__ w2l) {
    int idx = blockIdx.x * 256 + threadIdx.x;
    if (idx < 3*9*64*64) {
        int ci = idx & 63, co = (idx >> 6) & 63;
        int s  = (idx >> 12) % 9, br = idx / 36864;
        const float* src = (br == 0) ? cw1 : (br == 1 ? rw1 : ww1);
        float v = src[(co*64 + ci)*9 + s] * SCL_W;
        f16 h = (f16)v;
        w1h[idx] = h; w1l[idx] = (f16)(v - (float)h);
    }
    int j = idx - 3*9*64*64;
    if (j >= 0 && j < 112*64) {
        int ci = j & 63, row = j >> 6;
        float v = 0.f;
        if (row < 80)                    v = cw2[row*64 + ci];
        else if (row < 82)               v = rw2[(row-80)*64 + ci];
        else if (row >= 96 && row < 98)  v = ww2[(row-96)*64 + ci];
        v *= SCL_W;
        f16 h = (f16)v;
        w2h[j] = h; w2l[j] = (f16)(v - (float)h);
    }
}

// ---------------------------------------------------------------------------
// Fused MFMA conv. grid (h=2, y=128, b=16), block 256 (4 waves).
// r10 post-mortem: MfmaUtil 18% but occupancy fell to 1 wave/SIMD — the
// epilogue a2[5][2] on top of acc[3][8] (96 AGPR) + 132 VGPR crossed the
// 256-reg cliff (lesson #2 again, via the epilogue). r11: HALF-ROW blocks:
// wave w keeps co-tile [16w,+16) but px tile is 64 wide (m=0..3):
//   acc[3][4]=48 AGPR, epilogue a2[5]=20 -> ~180 total regs -> 2-3 waves/SIMD
//   LDS 19 KB (66-col A tile; borders staged inline, zeros when OOB)
// Accumulation order per px unchanged -> bit-identical outputs (absmax 0).
// ---------------------------------------------------------------------------
#define A_STRIDE 36                  // f16 per A row (32 ci + pad)
#define ABUF     9504                // bytes per A buffer (2 planes x 66 x 36 x 2B)
__global__ __launch_bounds__(256) void k_conv(
    const float* __restrict__ x,
    const f16* __restrict__ w1h, const f16* __restrict__ w1l,
    const f16* __restrict__ w2h, const f16* __restrict__ w2l,
    const float* __restrict__ b1c, const float* __restrict__ b1r, const float* __restrict__ b1w,
    const float* __restrict__ b2c, const float* __restrict__ b2r, const float* __restrict__ b2w,
    float* __restrict__ cls_o, float* __restrict__ reg_o, float* __restrict__ wh_o)
{
    __shared__ char smem[19008] __attribute__((aligned(16)));
    f16* Rh = (f16*)smem;                 // [64][72] hi (epilogue alias)
    f16* Rl = (f16*)(smem + 9216);        // [64][72] lo

    const int h = blockIdx.x, y = blockIdx.y, b = blockIdx.z;
    const int tid = threadIdx.x;
    const int w = tid >> 6, lane = tid & 63;
    const int l15 = lane & 15, quad = lane >> 4;

    static const int CS[6] = {0,0,0,1,1,1};
    static const int RS[6] = {0,1,2,0,1,2};

    // A tile rows 0..65: row i <-> global px  h*64 - 1 + i  (0 and 65 = borders)
    #define STAGE(bufi, si_) do {                                             \
        const int gy = y - 1 + RS[si_];                                       \
        const bool ok = (gy >= 0) && (gy < 128);                              \
        const float* xp = x + ((size_t)(b*64 + CS[si_]*32)*128 + gy)*128;     \
        f16x2* dh = (f16x2*)(smem + (bufi)*ABUF);                             \
        f16x2* dl = (f16x2*)(smem + (bufi)*ABUF + 4752);                      \
        _Pragma("unroll")                                                     \
        for (int e0 = 0; e0 < 1024; e0 += 256) {                              \
            int e = e0 + tid;                                                 \
            int pxl = e & 63, cp = e >> 6;                                    \
            float v0 = 0.f, v1 = 0.f;                                         \
            if (ok) { int g = h*64 + pxl;                                     \
                      v0 = xp[(size_t)(2*cp)*HWSZ + g]*SCL_X;                 \
                      v1 = xp[(size_t)(2*cp+1)*HWSZ + g]*SCL_X; }             \
            f16 h0 = (f16)v0, h1 = (f16)v1;                                   \
            f16 l0 = (f16)(v0 - (float)h0), l1 = (f16)(v1 - (float)h1);       \
            int wi = (pxl + 1)*18 + cp;                                       \
            dh[wi] = (f16x2){h0, h1};                                         \
            dl[wi] = (f16x2){l0, l1};                                         \
        }                                                                     \
        if (tid < 32) {                                                       \
            int side = tid >> 4, cp = tid & 15;                               \
            bool valid = ok && (side ? (h == 0) : (h == 1));                  \
            int g = side ? 64 : 63;  /* h=0 right px 64; h=1 left px 63 */    \
            float v0 = 0.f, v1 = 0.f;                                         \
            if (valid) { v0 = xp[(size_t)(2*cp)*HWSZ + g]*SCL_X;              \
                         v1 = xp[(size_t)(2*cp+1)*HWSZ + g]*SCL_X; }          \
            f16 h0 = (f16)v0, h1 = (f16)v1;                                   \
            f16 l0 = (f16)(v0 - (float)h0), l1 = (f16)(v1 - (float)h1);       \
            int wi = (side ? 65 : 0)*18 + cp;                                 \
            dh[wi] = (f16x2){h0, h1};                                         \
            dl[wi] = (f16x2){l0, l1};                                         \
        }                                                                     \
    } while (0)

    f32x4 acc[3][4];
    #pragma unroll
    for (int br = 0; br < 3; br++)
        #pragma unroll
        for (int m = 0; m < 4; m++) acc[br][m] = (f32x4){0.f,0.f,0.f,0.f};

    STAGE(0, 0);
    __syncthreads();

    // ======================= conv1: single pass, all branches =======================
    for (int si = 0; si < 6; si++) {
        const int cur = si & 1;
        if (si < 5) STAGE(cur ^ 1, si + 1);     // overlaps compute below
        const f16* APh = (const f16*)(smem + cur*ABUF);
        const f16* APl = APh + 2376;
        const int chunk = CS[si], r = RS[si];
        #pragma unroll
        for (int dx = 0; dx < 3; dx++) {
            const int s = r*3 + dx;
            // B fragments: wave w's co-tile, all 3 branches (6 loads -> 36 MFMAs)
            f16x8 bh[3], bl[3];
            #pragma unroll
            for (int br = 0; br < 3; br++) {
                size_t k = ((size_t)((br*9 + s)*64 + (w*16 + l15)))*64 + chunk*32 + quad*8;
                bh[br] = *(const f16x8*)(w1h + k);
                bl[br] = *(const f16x8*)(w1l + k);
            }
            #pragma unroll
            for (int m = 0; m < 4; m++) {
                int off = (m*16 + l15 + dx)*A_STRIDE + quad*8;
                f16x4 h0 = *(const f16x4*)(APh + off);
                f16x4 h1 = *(const f16x4*)(APh + off + 4);
                f16x4 u0 = *(const f16x4*)(APl + off);
                f16x4 u1 = *(const f16x4*)(APl + off + 4);
                f16x8 ah = __builtin_shufflevector(h0, h1, 0,1,2,3,4,5,6,7);
                f16x8 al = __builtin_shufflevector(u0, u1, 0,1,2,3,4,5,6,7);
                #pragma unroll
                for (int br = 0; br < 3; br++) {
                    acc[br][m] = __builtin_amdgcn_mfma_f32_16x16x32_f16(ah, bh[br], acc[br][m], 0,0,0);
                    acc[br][m] = __builtin_amdgcn_mfma_f32_16x16x32_f16(ah, bl[br], acc[br][m], 0,0,0);
                    acc[br][m] = __builtin_amdgcn_mfma_f32_16x16x32_f16(al, bh[br], acc[br][m], 0,0,0);
                }
            }
        }
        __syncthreads();   // staging of cur^1 visible; all reads of cur done
    }
    #undef STAGE

    // ======================= epilogue per branch =======================
    #pragma unroll
    for (int br = 0; br < 3; br++) {
        const float* b1 = (br == 0) ? b1c : (br == 1 ? b1r : b1w);
        const float b1v = b1[w*16 + l15];
        __syncthreads();                 // prior A use / prior conv2 reads done
        // R write: C layout (pxl = m*16+quad*4+rg, co = w*16+l15) -> A layout
        #pragma unroll
        for (int m = 0; m < 4; m++)
            #pragma unroll
            for (int rg = 0; rg < 4; rg++) {
                float t = fmaxf(acc[br][m][rg]*INV_ACC + b1v, 0.f) * SCL_X;
                f16 hh = (f16)t;
                int pxl = m*16 + quad*4 + rg;
                int co  = w*16 + l15;
                Rh[pxl*72 + co] = hh;
                Rl[pxl*72 + co] = (f16)(t - (float)hh);
            }
        __syncthreads();

        const int NT     = (br == 0) ? 5 : 1;
        const int rowoff = (br == 0) ? 0 : (br == 1 ? 80 : 96);
        f32x4 a2[5];
        #pragma unroll
        for (int n = 0; n < 5; n++) a2[n] = (f32x4){0.f,0.f,0.f,0.f};

        // wave w computes local px tile [16w, 16w+16)
        #pragma unroll
        for (int kc = 0; kc < 64; kc += 32) {
            int off = (w*16 + l15)*72 + kc + quad*8;
            f16x4 h0 = *(const f16x4*)(Rh + off);
            f16x4 h1 = *(const f16x4*)(Rh + off + 4);
            f16x4 u0 = *(const f16x4*)(Rl + off);
            f16x4 u1 = *(const f16x4*)(Rl + off + 4);
            f16x8 xh = __builtin_shufflevector(h0, h1, 0,1,2,3,4,5,6,7);
            f16x8 xl = __builtin_shufflevector(u0, u1, 0,1,2,3,4,5,6,7);
            #pragma unroll
            for (int n = 0; n < 5; n++) {
                if (n >= NT) break;
                const f16* g2h = w2h + (rowoff + n*16 + l15)*64 + kc + quad*8;
                const f16* g2l = w2l + (rowoff + n*16 + l15)*64 + kc + quad*8;
                f16x8 bh = *(const f16x8*)g2h;
                f16x8 bl = *(const f16x8*)g2l;
                a2[n] = __builtin_amdgcn_mfma_f32_16x16x32_f16(xh, bh, a2[n], 0,0,0);
                a2[n] = __builtin_amdgcn_mfma_f32_16x16x32_f16(xh, bl, a2[n], 0,0,0);
                a2[n] = __builtin_amdgcn_mfma_f32_16x16x32_f16(xl, bh, a2[n], 0,0,0);
            }
        }

        const int pxg = h*64 + w*16 + quad*4;    // +rg
        if (br == 0) {
            #pragma unroll
            for (int n = 0; n < 5; n++) {
                int co2 = n*16 + l15;
                float bb = b2c[co2];
                #pragma unroll
                for (int rg = 0; rg < 4; rg++) {
                    float sv = a2[n][rg]*INV_ACC + bb;
                    cls_o[((size_t)(b*80 + co2)*128 + y)*128 + pxg + rg] = 1.f/(1.f + expf(-sv));
                }
            }
        } else {
            if (l15 < 2) {
                const float* b2 = (br == 1) ? b2r : b2w;
                float* outp     = (br == 1) ? reg_o : wh_o;
                float bb = b2[l15];
                #pragma unroll
                for (int rg = 0; rg < 4; rg++) {
                    float sv = a2[0][rg]*INV_ACC + bb;
                    float o  = (br == 1) ? (1.f/(1.f + expf(-sv))) : expf(sv);
                    outp[((size_t)(b*2 + l15))*HWSZ + y*128 + pxg + rg] = o;
                }
            }
        }
    }
}

// ---------------------------------------------------------------------------
// 3x3 peak mask + max/argmax over classes — barrier-free (r5 config, verified).
// ---------------------------------------------------------------------------
__global__ __launch_bounds__(256) void k_peaks(const float* __restrict__ cls,
                                               float* __restrict__ sc,
                                               int* __restrict__ cat) {
    const int b  = blockIdx.y;
    const int wv = threadIdx.x >> 6;
    const int l  = threadIdx.x & 63;
    const int y  = blockIdx.x * 4 + wv;
    const int p0 = l * 2;
    const bool yt = (y > 0), yb = (y < 127);
    float best0 = -1.f, best1 = -1.f;
    int bc0 = 0, bc1 = 0;
    for (int c = 0; c < 80; c++) {
        const float* pl = cls + (size_t)(b*80 + c)*HWSZ + y*128 + p0;
        float2 cur = *(const float2*)pl;
        float2 tp  = yt ? *(const float2*)(pl - 128) : make_float2(-1e30f, -1e30f);
        float2 bt  = yb ? *(const float2*)(pl + 128) : make_float2(-1e30f, -1e30f);
        float vm0 = fmaxf(cur.x, fmaxf(tp.x, bt.x));
        float vm1 = fmaxf(cur.y, fmaxf(tp.y, bt.y));
        float lft = __shfl_up(vm1, 1);   if (l == 0)  lft = -1e30f;
        float rgt = __shfl_down(vm0, 1); if (l == 63) rgt = -1e30f;
        float m0 = fmaxf(lft, fmaxf(vm0, vm1));
        float m1 = fmaxf(vm0, fmaxf(vm1, rgt));
        float k0 = (cur.x == m0) ? cur.x : 0.f;
        float k1 = (cur.y == m1) ? cur.y : 0.f;
        if (k0 > best0) { best0 = k0; bc0 = c; }   // strict > == first-max
        if (k1 > best1) { best1 = k1; bc1 = c; }
    }
    int o = b*HWSZ + y*128 + p0;
    *(float2*)&sc[o] = make_float2(best0, best1);
    *(int2*)&cat[o]  = make_int2(bc0, bc1);
}

// ---------------------------------------------------------------------------
// Fused per-batch top-100 + box decode + NMS + all outputs (r8, verified).
// ---------------------------------------------------------------------------
__global__ void k_select(const float* __restrict__ sc, const int* __restrict__ cats,
                         const float* __restrict__ regp, const float* __restrict__ whp,
                         float* __restrict__ out) {
    const int b   = blockIdx.x;
    const int tid = threadIdx.x;
    const float* scb = sc + (size_t)b*HWSZ;

    __shared__ float cmax[64];
    __shared__ int   cidx[64];
    __shared__ uint  selmask[512];      // 16384 bits
    __shared__ int   s_inds[KK];
    __shared__ float s_vals[KK];
    __shared__ float X1[KK], Y1[KK], X2[KK], Y2[KK], AR[KK];

    selmask[tid] = 0u; selmask[tid + 256] = 0u;

    {   // Phase A: per-chunk max (value desc, first index)
        int c = tid >> 2, q = tid & 3;
        int base = c*256 + q*64;
        float bv = -1e30f; int bi = base;
        for (int e = 0; e < 64; e++) {
            float v = scb[base + e];
            if (v > bv) { bv = v; bi = base + e; }
        }
        #pragma unroll
        for (int off = 1; off <= 2; off <<= 1) {
            float ov = __shfl_xor(bv, off);
            int   oi = __shfl_xor(bi, off);
            if (ov > bv || (ov == bv && oi < bi)) { bv = ov; bi = oi; }
        }
        if (q == 0) { cmax[c] = bv; cidx[c] = bi; }
    }
    __syncthreads();

    if (tid < 64) {  // Phase B: 100 selections, wave 0
        const int l = tid;
        float v = cmax[l]; int ix = cidx[l];
        for (int it = 0; it < KK; it++) {
            float rv = v; int ri = ix;
            #pragma unroll
            for (int off = 32; off >= 1; off >>= 1) {
                float ov = __shfl_down(rv, off);
                int   oi = __shfl_down(ri, off);
                if (ov > rv || (ov == rv && oi < ri)) { rv = ov; ri = oi; }
            }
            float fv = __shfl(rv, 0);
            int   fi = __shfl(ri, 0);
            if (l == 0) {
                s_inds[it] = fi; s_vals[it] = fv;
                atomicOr(&selmask[fi >> 5], 1u << (fi & 31));
            }
            __threadfence_block();
            int wc = fi >> 8;
            int eb = wc*256 + l*4;
            uint mw = selmask[wc*8 + (l >> 3)];
            float nv = -1e30f; int ni = eb;
            #pragma unroll
            for (int r = 0; r < 4; r++) {
                float u = scb[eb + r];
                bool masked = (mw >> (((l & 7)*4 + r))) & 1u;
                if (!masked && u > nv) { nv = u; ni = eb + r; }
            }
            #pragma unroll
            for (int off = 32; off >= 1; off >>= 1) {
                float ov = __shfl_down(nv, off);
                int   oi = __shfl_down(ni, off);
                if (ov > nv || (ov == nv && oi < ni)) { nv = ov; ni = oi; }
            }
            float cv = __shfl(nv, 0);
            int   ci2 = __shfl(ni, 0);
            if (l == wc) { v = cv; ix = ci2; }
        }
    }
    __syncthreads();

    if (tid < KK) {  // Phase C: decode boxes
        int ind   = s_inds[tid];
        float scv = s_vals[tid];
        const float* rb = regp + (size_t)b*2*HWSZ;
        const float* wb = whp  + (size_t)b*2*HWSZ;
        float r0 = rb[ind], r1 = rb[HWSZ + ind];
        float w0 = wb[ind], w1 = wb[HWSZ + ind];
        float ctx = (float)(ind & 127) + r0;
        float cty = (float)(ind >> 7) + r1;
        float x1 = (ctx - w0*0.5f)*4.f, y1 = (cty - w1*0.5f)*4.f;
        float x2 = (ctx + w0*0.5f)*4.f, y2 = (cty + w1*0.5f)*4.f;
        size_t bo = ((size_t)b*KK + tid)*4;
        out[bo+0] = x1; out[bo+1] = y1; out[bo+2] = x2; out[bo+3] = y2;
        out[BN*KK*4 + b*KK + tid]         = (float)cats[(size_t)b*HWSZ + ind];
        out[BN*KK*4 + BN*KK + b*KK + tid] = scv;
        X1[tid] = x1; Y1[tid] = y1; X2[tid] = x2; Y2[tid] = y2;
        AR[tid] = (x2 - x1)*(y2 - y1);
    }
    __syncthreads();

    if (tid < 64) {  // Phase D: NMS in wave 0
        const int l = tid;
        float x1a = X1[l], y1a = Y1[l], x2a = X2[l], y2a = Y2[l], ara = AR[l];
        int   ka  = (s_vals[l] > 0.2f) ? 1 : 0;
        float x1b = 0, y1b = 0, x2b = 0, y2b = 0, arb = 0;
        int   kb  = 0;
        if (l < KK - 64) {
            x1b = X1[64+l]; y1b = Y1[64+l]; x2b = X2[64+l]; y2b = Y2[64+l];
            arb = AR[64+l];
            kb  = (s_vals[64+l] > 0.2f) ? 1 : 0;
        }
        for (int i = 0; i < KK; i++) {
            float jx1, jy1, jx2, jy2, jar; int jk;
            if (i < 64) {
                jx1 = __shfl(x1a, i); jy1 = __shfl(y1a, i);
                jx2 = __shfl(x2a, i); jy2 = __shfl(y2a, i);
                jar = __shfl(ara, i); jk  = __shfl(ka,  i);
            } else {
                int li = i - 64;
                jx1 = __shfl(x1b, li); jy1 = __shfl(y1b, li);
                jx2 = __shfl(x2b, li); jy2 = __shfl(y2b, li);
                jar = __shfl(arb, li); jk  = __shfl(kb,  li);
            }
            if (jk) {
                if (ka && l > i) {
                    float iw = fminf(jx2, x2a) - fmaxf(jx1, x1a); iw = iw > 0.f ? iw : 0.f;
                    float ih = fminf(jy2, y2a) - fmaxf(jy1, y1a); ih = ih > 0.f ? ih : 0.f;
                    float inter = iw*ih;
                    float iou = inter / (jar + ara - inter + 1e-9f);
                    if (iou > 0.5f) ka = 0;
                }
                if (kb && (64 + l) > i) {
                    float iw = fminf(jx2, x2b) - fmaxf(jx1, x1b); iw = iw > 0.f ? iw : 0.f;
                    float ih = fminf(jy2, y2b) - fmaxf(jy1, y1b); ih = ih > 0.f ? ih : 0.f;
                    float inter = iw*ih;
                    float iou = inter / (jar + arb - inter + 1e-9f);
                    if (iou > 0.5f) kb = 0;
                }
            }
        }
        int koff = BN*KK*4 + 2*BN*KK;
        out[koff + b*KK + l] = ka ? 1.f : 0.f;
        if (l < KK - 64) out[koff + b*KK + 64 + l] = kb ? 1.f : 0.f;
    }
}

// ---------------------------------------------------------------------------
extern "C" void kernel_launch(void* const* d_in, const int* in_sizes, int n_in,
                              void* d_out, int out_size, void* d_ws, size_t ws_size,
                              hipStream_t stream) {
    const float* x      = (const float*)d_in[0];
    const float* cls_w1 = (const float*)d_in[1];
    const float* cls_b1 = (const float*)d_in[2];
    const float* cls_w2 = (const float*)d_in[3];
    const float* cls_b2 = (const float*)d_in[4];
    const float* reg_w1 = (const float*)d_in[5];
    const float* reg_b1 = (const float*)d_in[6];
    const float* reg_w2 = (const float*)d_in[7];
    const float* reg_b2 = (const float*)d_in[8];
    const float* wh_w1  = (const float*)d_in[9];
    const float* wh_b1  = (const float*)d_in[10];
    const float* wh_w2  = (const float*)d_in[11];
    const float* wh_b2  = (const float*)d_in[12];

    float* ws   = (float*)d_ws;
    float* clsb = ws + WS_CLS;
    float* regb = ws + WS_REG;
    float* whb  = ws + WS_WH;
    float* scw  = ws + WS_SC;
    int*   cat  = (int*)(ws + WS_CAT);
    f16*   w1h  = (f16*)(ws + WS_W1H);
    f16*   w1l  = (f16*)(ws + WS_W1L);
    f16*   w2h  = (f16*)(ws + WS_W2H);
    f16*   w2l  = (f16*)(ws + WS_W2L);
    float* out  = (float*)d_out;

    k_prep<<<(3*9*64*64 + 112*64 + 255)/256, 256, 0, stream>>>(
        cls_w1, reg_w1, wh_w1, cls_w2, reg_w2, wh_w2, w1h, w1l, w2h, w2l);
    k_conv<<<dim3(2, 128, 16), 256, 0, stream>>>(
        x, w1h, w1l, w2h, w2l, cls_b1, reg_b1, wh_b1,
        cls_b2, reg_b2, wh_b2, clsb, regb, whb);
    k_peaks<<<dim3(32, 16), 256, 0, stream>>>(clsb, scw, cat);
    k_select<<<16, 256, 0, stream>>>(scw, cat, regb, whb, out);
}